// Round 1
// baseline (437.374 us; speedup 1.0000x reference)
//
#include <hip/hip_runtime.h>
#include <hip/hip_bf16.h>

typedef short short8 __attribute__((ext_vector_type(8)));
typedef short short4v __attribute__((ext_vector_type(4)));
typedef float floatx4 __attribute__((ext_vector_type(4)));

constexpr int Bc = 2, Sc = 4096, Dc = 512, Hc = 8, DKc = 64;
constexpr int Mc = Bc * Sc;  // 8192

static __device__ __forceinline__ unsigned short f2bf(float f) {
  // round-to-nearest-even f32 -> bf16
  unsigned int u = __builtin_bit_cast(unsigned int, f);
  unsigned int rb = ((u >> 16) & 1u) + 0x7fffu;
  return (unsigned short)((u + rb) >> 16);
}

// ---------------- weight cast: 4x [D,D] f32 -> bf16 (contiguous in ws) ------
__global__ __launch_bounds__(256) void cast_w(
    const float* __restrict__ a, const float* __restrict__ b,
    const float* __restrict__ c, const float* __restrict__ d,
    unsigned short* __restrict__ out) {
  const float* srcs[4] = {a, b, c, d};
  const int m = blockIdx.y;
  const int i = (blockIdx.x * 256 + threadIdx.x) * 4;
  float4 v = *(const float4*)(srcs[m] + i);
  unsigned short t4[4] = {f2bf(v.x), f2bf(v.y), f2bf(v.z), f2bf(v.w)};
  *(short4v*)(out + (size_t)m * (Dc * Dc) + i) = *(short4v*)t4;
}

// ---------------- GEMM: Y[M,N] = X[M,K] @ W[N,K]^T  (torch Linear) ----------
// IN_F32: X is f32 (converted to bf16 during staging) else bf16.
// OUT_F32: Y written f32 else bf16.
template <int IN_F32, int OUT_F32>
__global__ __launch_bounds__(256) void gemm_bt(
    const void* __restrict__ Xv, const unsigned short* __restrict__ Wb,
    void* __restrict__ Yv, int Mdim, int N, int K) {
  constexpr int BM = 128, BN = 128, BK = 32, LDP = 40;  // pad: 80B pitch, 16B aligned
  __shared__ unsigned short As[BM * LDP];
  __shared__ unsigned short Bs[BN * LDP];
  const int tid = threadIdx.x;
  const int lane = tid & 63, wid = tid >> 6;
  const int wm = wid >> 1, wn = wid & 1;  // 2x2 waves of 64x64
  const int bm = blockIdx.y * BM, bn = blockIdx.x * BN;
  const int rq = lane & 15, kk8 = (lane >> 4) * 8;
  const int sr = tid >> 1;           // staging row 0..127
  const int sc = (tid & 1) * 16;     // staging col 0 or 16

  floatx4 acc[4][4] = {};

  for (int k0 = 0; k0 < K; k0 += BK) {
    if (IN_F32) {
      const float* src = (const float*)Xv + (size_t)(bm + sr) * K + k0 + sc;
      unsigned short tmp[16];
#pragma unroll
      for (int i = 0; i < 4; ++i) {
        float4 v = *(const float4*)(src + i * 4);
        tmp[i * 4 + 0] = f2bf(v.x);
        tmp[i * 4 + 1] = f2bf(v.y);
        tmp[i * 4 + 2] = f2bf(v.z);
        tmp[i * 4 + 3] = f2bf(v.w);
      }
      *(short8*)&As[sr * LDP + sc] = *(short8*)&tmp[0];
      *(short8*)&As[sr * LDP + sc + 8] = *(short8*)&tmp[8];
    } else {
      const unsigned short* src =
          (const unsigned short*)Xv + (size_t)(bm + sr) * K + k0 + sc;
      *(short8*)&As[sr * LDP + sc] = *(const short8*)src;
      *(short8*)&As[sr * LDP + sc + 8] = *(const short8*)(src + 8);
    }
    const unsigned short* bsrc = Wb + (size_t)(bn + sr) * K + k0 + sc;
    *(short8*)&Bs[sr * LDP + sc] = *(const short8*)bsrc;
    *(short8*)&Bs[sr * LDP + sc + 8] = *(const short8*)(bsrc + 8);
    __syncthreads();

    short8 af[4], bfr[4];
#pragma unroll
    for (int mi = 0; mi < 4; ++mi)
      af[mi] = *(const short8*)&As[(wm * 64 + mi * 16 + rq) * LDP + kk8];
#pragma unroll
    for (int ni = 0; ni < 4; ++ni)
      bfr[ni] = *(const short8*)&Bs[(wn * 64 + ni * 16 + rq) * LDP + kk8];
#pragma unroll
    for (int mi = 0; mi < 4; ++mi)
#pragma unroll
      for (int ni = 0; ni < 4; ++ni)
        acc[mi][ni] = __builtin_amdgcn_mfma_f32_16x16x32_bf16(
            af[mi], bfr[ni], acc[mi][ni], 0, 0, 0);
    __syncthreads();
  }

#pragma unroll
  for (int mi = 0; mi < 4; ++mi)
#pragma unroll
    for (int ni = 0; ni < 4; ++ni)
#pragma unroll
      for (int j = 0; j < 4; ++j) {
        // C/D layout: col = lane&15, row = (lane>>4)*4 + j   [m89-verified]
        int r = bm + wm * 64 + mi * 16 + (lane >> 4) * 4 + j;
        int c = bn + wn * 64 + ni * 16 + rq;
        float v = acc[mi][ni][j];
        if (OUT_F32)
          ((float*)Yv)[(size_t)r * N + c] = v;
        else
          ((unsigned short*)Yv)[(size_t)r * N + c] = f2bf(v);
      }
}

// ---------------- flash attention ------------------------------------------
// Q,K,V,O: bf16 [B,S,D], head h occupies columns h*64..h*64+63.
// Block: 256 threads (4 waves); wave handles 32 q-rows; block = 128 q-rows.
// Loop over 32-key blocks with online softmax.
__global__ __launch_bounds__(256) void attn_fwd(
    const unsigned short* __restrict__ Qp, const unsigned short* __restrict__ Kp,
    const unsigned short* __restrict__ Vp, unsigned short* __restrict__ Op) {
  constexpr int KB = 32;
  constexpr int LDK = 72;  // K tile pitch (144B rows, 16B aligned, conflict-free)
  constexpr int LDV = 40;  // V^T tile pitch
  constexpr int LDPS = 40; // P tile pitch
  __shared__ unsigned short Ks[KB * LDK];       // [key][dk]
  __shared__ unsigned short Vt[DKc * LDV];      // [dk][key]
  __shared__ unsigned short Ps[4 * 2 * 16 * LDPS];

  const int tid = threadIdx.x, lane = tid & 63, wid = tid >> 6;
  const int b = blockIdx.y >> 3, h = blockIdx.y & 7;
  const int q0 = blockIdx.x * 128 + wid * 32;
  const int rq = lane & 15, kk8 = (lane >> 4) * 8;

  const unsigned short* Qb = Qp + ((size_t)b * Sc) * Dc + h * DKc;
  const unsigned short* Kb = Kp + ((size_t)b * Sc) * Dc + h * DKc;
  const unsigned short* Vb = Vp + ((size_t)b * Sc) * Dc + h * DKc;

  // Q fragments held in registers for the whole kernel.
  // A-frag layout: row = lane&15, k = (lane>>4)*8 + j
  short8 qa[2][2];
#pragma unroll
  for (int qi = 0; qi < 2; ++qi)
#pragma unroll
    for (int c = 0; c < 2; ++c)
      qa[qi][c] = *(const short8*)(Qb + (size_t)(q0 + qi * 16 + rq) * Dc + c * 32 + kk8);

  float m_run[2][4], l_run[2][4];
  floatx4 o_acc[2][4] = {};
#pragma unroll
  for (int qi = 0; qi < 2; ++qi)
#pragma unroll
    for (int j = 0; j < 4; ++j) { m_run[qi][j] = -1e30f; l_run[qi][j] = 0.f; }

  // staging maps
  const int skey = tid >> 3, scol = (tid & 7) * 8;        // K: 8 threads/row
  const int vkey = tid & 31, vdk0 = (tid >> 5) * 8;       // V: 8 threads/row, transposed write

  for (int kb = 0; kb < Sc / KB; ++kb) {
    // stage K [32][64] row-major
    *(short8*)&Ks[skey * LDK + scol] =
        *(const short8*)(Kb + (size_t)(kb * KB + skey) * Dc + scol);
    // stage V transposed -> Vt[dk][key]
    short8 vv = *(const short8*)(Vb + (size_t)(kb * KB + vkey) * Dc + vdk0);
#pragma unroll
    for (int j = 0; j < 8; ++j) Vt[(vdk0 + j) * LDV + vkey] = (unsigned short)vv[j];
    __syncthreads();

    // B-frag for QK^T: B[k=dk][n=key] = K[key][dk] -> contiguous dk run per lane
    short8 bk[2][2];
#pragma unroll
    for (int ks = 0; ks < 2; ++ks)
#pragma unroll
      for (int c = 0; c < 2; ++c)
        bk[ks][c] = *(const short8*)&Ks[(ks * 16 + rq) * LDK + c * 32 + kk8];

#pragma unroll
    for (int qi = 0; qi < 2; ++qi) {
      floatx4 s0 = {0.f, 0.f, 0.f, 0.f}, s1 = {0.f, 0.f, 0.f, 0.f};
      s0 = __builtin_amdgcn_mfma_f32_16x16x32_bf16(qa[qi][0], bk[0][0], s0, 0, 0, 0);
      s0 = __builtin_amdgcn_mfma_f32_16x16x32_bf16(qa[qi][1], bk[0][1], s0, 0, 0, 0);
      s1 = __builtin_amdgcn_mfma_f32_16x16x32_bf16(qa[qi][0], bk[1][0], s1, 0, 0, 0);
      s1 = __builtin_amdgcn_mfma_f32_16x16x32_bf16(qa[qi][1], bk[1][1], s1, 0, 0, 0);

      float p0[4], p1[4], tm[4], rs[4];
#pragma unroll
      for (int j = 0; j < 4; ++j) {
        p0[j] = s0[j] * 0.125f;  // 1/sqrt(64)
        p1[j] = s1[j] * 0.125f;
        tm[j] = fmaxf(p0[j], p1[j]);
      }
      // row-max over the 16 lanes holding this row's 16 cols
#pragma unroll
      for (int mask = 1; mask <= 8; mask <<= 1)
#pragma unroll
        for (int j = 0; j < 4; ++j)
          tm[j] = fmaxf(tm[j], __shfl_xor(tm[j], mask, 64));
#pragma unroll
      for (int j = 0; j < 4; ++j) {
        float mn = fmaxf(m_run[qi][j], tm[j]);
        float scf = __expf(m_run[qi][j] - mn);
        p0[j] = __expf(p0[j] - mn);
        p1[j] = __expf(p1[j] - mn);
        rs[j] = p0[j] + p1[j];
        m_run[qi][j] = mn;
        l_run[qi][j] *= scf;
#pragma unroll
        for (int d = 0; d < 4; ++d) o_acc[qi][d][j] *= scf;
      }
#pragma unroll
      for (int mask = 1; mask <= 8; mask <<= 1)
#pragma unroll
        for (int j = 0; j < 4; ++j)
          rs[j] += __shfl_xor(rs[j], mask, 64);
#pragma unroll
      for (int j = 0; j < 4; ++j) l_run[qi][j] += rs[j];
      // spill P (C-layout) to LDS so PV can read it in A-layout
#pragma unroll
      for (int j = 0; j < 4; ++j) {
        int pr = (lane >> 4) * 4 + j;
        Ps[((wid * 2 + qi) * 16 + pr) * LDPS + rq] = f2bf(p0[j]);
        Ps[((wid * 2 + qi) * 16 + pr) * LDPS + 16 + rq] = f2bf(p1[j]);
      }
    }
    __syncthreads();

    // PV: A = P[16q x 32keys], B[k=key][n=dk] = V[key][dk] = Vt[dk][key]
#pragma unroll
    for (int d = 0; d < 4; ++d) {
      short8 bv = *(const short8*)&Vt[(d * 16 + rq) * LDV + kk8];
#pragma unroll
      for (int qi = 0; qi < 2; ++qi) {
        short8 pa = *(const short8*)&Ps[((wid * 2 + qi) * 16 + rq) * LDPS + kk8];
        o_acc[qi][d] = __builtin_amdgcn_mfma_f32_16x16x32_bf16(pa, bv, o_acc[qi][d], 0, 0, 0);
      }
    }
    __syncthreads();
  }

#pragma unroll
  for (int qi = 0; qi < 2; ++qi)
#pragma unroll
    for (int j = 0; j < 4; ++j) {
      float inv = 1.0f / l_run[qi][j];
      int r = q0 + qi * 16 + (lane >> 4) * 4 + j;
#pragma unroll
      for (int d = 0; d < 4; ++d) {
        float v = o_acc[qi][d][j] * inv;
        Op[((size_t)b * Sc + r) * Dc + h * DKc + d * 16 + rq] = f2bf(v);
      }
    }
}

// ---------------- launcher --------------------------------------------------
extern "C" void kernel_launch(void* const* d_in, const int* in_sizes, int n_in,
                              void* d_out, int out_size, void* d_ws, size_t ws_size,
                              hipStream_t stream) {
  const float* q_in = (const float*)d_in[0];
  const float* k_in = (const float*)d_in[1];
  const float* v_in = (const float*)d_in[2];
  const float* Wq = (const float*)d_in[3];
  const float* Wk = (const float*)d_in[4];
  const float* Wv = (const float*)d_in[5];
  const float* Wo = (const float*)d_in[6];

  unsigned short* wq_b = (unsigned short*)d_ws;  // 4 weights, contiguous
  unsigned short* wk_b = wq_b + Dc * Dc;
  unsigned short* wv_b = wk_b + Dc * Dc;
  unsigned short* wo_b = wv_b + Dc * Dc;
  unsigned short* qb = wo_b + Dc * Dc;           // [M,D] bf16
  unsigned short* kb = qb + (size_t)Mc * Dc;
  unsigned short* vb = kb + (size_t)Mc * Dc;
  unsigned short* ab = vb + (size_t)Mc * Dc;     // attention output, bf16

  // 1) cast weights
  dim3 cg(Dc * Dc / 4 / 256, 4);
  cast_w<<<cg, 256, 0, stream>>>(Wq, Wk, Wv, Wo, wq_b);

  // 2) projections (f32 in, bf16 out)
  dim3 gg(Dc / 128, Mc / 128);  // (4, 64)
  gemm_bt<1, 0><<<gg, 256, 0, stream>>>(q_in, wq_b, qb, Mc, Dc, Dc);
  gemm_bt<1, 0><<<gg, 256, 0, stream>>>(k_in, wk_b, kb, Mc, Dc, Dc);
  gemm_bt<1, 0><<<gg, 256, 0, stream>>>(v_in, wv_b, vb, Mc, Dc, Dc);

  // 3) attention
  dim3 ga(Sc / 128, Bc * Hc);  // (32, 16)
  attn_fwd<<<ga, 256, 0, stream>>>(qb, kb, vb, ab);

  // 4) output projection (bf16 in, f32 out)
  gemm_bt<0, 1><<<gg, 256, 0, stream>>>(ab, wo_b, (float*)d_out, Mc, Dc, Dc);
}

// Round 4
// 264.062 us; speedup vs baseline: 1.6563x; 1.6563x over previous
//
#include <hip/hip_runtime.h>
#include <hip/hip_bf16.h>

typedef short short8 __attribute__((ext_vector_type(8)));
typedef short short4v __attribute__((ext_vector_type(4)));
typedef float floatx4 __attribute__((ext_vector_type(4)));

constexpr int Bc = 2, Sc = 4096, Dc = 512, Hc = 8, DKc = 64;
constexpr int Mc = Bc * Sc;  // 8192

static __device__ __forceinline__ unsigned short f2bf(float f) {
  unsigned int u = __builtin_bit_cast(unsigned int, f);
  unsigned int rb = ((u >> 16) & 1u) + 0x7fffu;
  return (unsigned short)((u + rb) >> 16);
}

// ---------------- weight cast ------------------------------------------------
__global__ __launch_bounds__(256) void cast_w(
    const float* __restrict__ a, const float* __restrict__ b,
    const float* __restrict__ c, const float* __restrict__ d,
    unsigned short* __restrict__ out) {
  const float* srcs[4] = {a, b, c, d};
  const int m = blockIdx.y;
  const int i = (blockIdx.x * 256 + threadIdx.x) * 4;
  float4 v = *(const float4*)(srcs[m] + i);
  unsigned short t4[4] = {f2bf(v.x), f2bf(v.y), f2bf(v.z), f2bf(v.w)};
  *(short4v*)(out + (size_t)m * (Dc * Dc) + i) = *(short4v*)t4;
}

// ---------------- GEMM: Y[M,N] = X[M,K] @ W[N,K]^T ---------------------------
template <int IN_F32, int OUT_F32>
__global__ __launch_bounds__(256) void gemm_bt(
    const void* __restrict__ Xv, const unsigned short* __restrict__ Wb,
    void* __restrict__ Yv, int Mdim, int N, int K) {
  constexpr int BM = 128, BN = 128, BK = 32, LDP = 40;
  __shared__ unsigned short As[BM * LDP];
  __shared__ unsigned short Bs[BN * LDP];
  const int tid = threadIdx.x;
  const int lane = tid & 63, wid = tid >> 6;
  const int wm = wid >> 1, wn = wid & 1;
  const int bm = blockIdx.y * BM, bn = blockIdx.x * BN;
  const int rq = lane & 15, kk8 = (lane >> 4) * 8;
  const int sr = tid >> 1;
  const int sc = (tid & 1) * 16;

  floatx4 acc[4][4] = {};

  for (int k0 = 0; k0 < K; k0 += BK) {
    if (IN_F32) {
      const float* src = (const float*)Xv + (size_t)(bm + sr) * K + k0 + sc;
      unsigned short tmp[16];
#pragma unroll
      for (int i = 0; i < 4; ++i) {
        float4 v = *(const float4*)(src + i * 4);
        tmp[i * 4 + 0] = f2bf(v.x);
        tmp[i * 4 + 1] = f2bf(v.y);
        tmp[i * 4 + 2] = f2bf(v.z);
        tmp[i * 4 + 3] = f2bf(v.w);
      }
      *(short8*)&As[sr * LDP + sc] = *(short8*)&tmp[0];
      *(short8*)&As[sr * LDP + sc + 8] = *(short8*)&tmp[8];
    } else {
      const unsigned short* src =
          (const unsigned short*)Xv + (size_t)(bm + sr) * K + k0 + sc;
      *(short8*)&As[sr * LDP + sc] = *(const short8*)src;
      *(short8*)&As[sr * LDP + sc + 8] = *(const short8*)(src + 8);
    }
    const unsigned short* bsrc = Wb + (size_t)(bn + sr) * K + k0 + sc;
    *(short8*)&Bs[sr * LDP + sc] = *(const short8*)bsrc;
    *(short8*)&Bs[sr * LDP + sc + 8] = *(const short8*)(bsrc + 8);
    __syncthreads();

    short8 af[4], bfr[4];
#pragma unroll
    for (int mi = 0; mi < 4; ++mi)
      af[mi] = *(const short8*)&As[(wm * 64 + mi * 16 + rq) * LDP + kk8];
#pragma unroll
    for (int ni = 0; ni < 4; ++ni)
      bfr[ni] = *(const short8*)&Bs[(wn * 64 + ni * 16 + rq) * LDP + kk8];
#pragma unroll
    for (int mi = 0; mi < 4; ++mi)
#pragma unroll
      for (int ni = 0; ni < 4; ++ni)
        acc[mi][ni] = __builtin_amdgcn_mfma_f32_16x16x32_bf16(
            af[mi], bfr[ni], acc[mi][ni], 0, 0, 0);
    __syncthreads();
  }

#pragma unroll
  for (int mi = 0; mi < 4; ++mi)
#pragma unroll
    for (int ni = 0; ni < 4; ++ni)
#pragma unroll
      for (int j = 0; j < 4; ++j) {
        int r = bm + wm * 64 + mi * 16 + (lane >> 4) * 4 + j;
        int c = bn + wn * 64 + ni * 16 + rq;
        float v = acc[mi][ni][j];
        if (OUT_F32)
          ((float*)Yv)[(size_t)r * N + c] = v;
        else
          ((unsigned short*)Yv)[(size_t)r * N + c] = f2bf(v);
      }
}

// ---------------- V transpose: vt[b][c][s] = vb[b][s][c] ---------------------
__global__ __launch_bounds__(256) void transpose_v(
    const unsigned short* __restrict__ vb, unsigned short* __restrict__ vt) {
  constexpr int LDT = 65;  // odd pitch: 2-way max on column reads
  __shared__ unsigned short T[64 * LDT];
  const int tid = threadIdx.x;
  const int s0 = blockIdx.x * 64, c0 = blockIdx.y * 64, b = blockIdx.z;
  const int r = tid >> 2, cs = (tid & 3) * 16;
  const unsigned short* src = vb + ((size_t)b * Sc + s0 + r) * Dc + c0 + cs;
  *(short8*)&T[r * LDT + cs] = *(const short8*)src;
  *(short8*)&T[r * LDT + cs + 8] = *(const short8*)(src + 8);
  __syncthreads();
  unsigned short* dst = vt + ((size_t)b * Dc + c0 + r) * Sc + s0 + cs;
  unsigned short tmp[16];
#pragma unroll
  for (int j = 0; j < 16; ++j) tmp[j] = T[(cs + j) * LDT + r];
  *(short8*)dst = *(short8*)&tmp[0];
  *(short8*)(dst + 8) = *(short8*)&tmp[8];
}

// ---------------- flash attention (k-split, KB=64) ---------------------------
// 512 threads = 8 waves. Waves 0-3 (group 0) process keys [0, S/2),
// waves 4-7 (group 1) keys [S/2, S). Each wave owns 32 q-rows. Merge at end.
__global__ __launch_bounds__(512, 4) void attn_fwd(
    const unsigned short* __restrict__ Qp, const unsigned short* __restrict__ Kp,
    const unsigned short* __restrict__ Vtp, unsigned short* __restrict__ Op) {
  constexpr int KB = 64, LDK = 72, LDV = 72, LDPS = 72;
  __shared__ unsigned short Ks[2][KB * LDK];
  __shared__ unsigned short Vs[2][DKc * LDV];
  __shared__ unsigned short Ps[2][4 * 32 * LDPS];

  const int tid = threadIdx.x, lane = tid & 63, wid = tid >> 6;
  const int g = wid >> 2, w = wid & 3;
  const int b = blockIdx.y >> 3, h = blockIdx.y & 7;
  const int q0 = blockIdx.x * 128 + w * 32;
  const int rq = lane & 15, lg = lane >> 4, kk8 = lg * 8;
  const int u = tid & 255;                 // thread id within group
  const int sr = u >> 2, scs = (u & 3) * 16;  // staging row / col

  const unsigned short* Qb = Qp + ((size_t)b * Sc) * Dc + h * DKc;
  const unsigned short* Kb = Kp + ((size_t)b * Sc) * Dc + h * DKc;
  const unsigned short* Vh = Vtp + ((size_t)b * Dc + h * DKc) * Sc;

  // Q fragments in registers (A-frag: row = lane&15, k = (lane>>4)*8+j)
  short8 qa[2][2];
#pragma unroll
  for (int qi = 0; qi < 2; ++qi)
#pragma unroll
    for (int c = 0; c < 2; ++c)
      qa[qi][c] = *(const short8*)(Qb + (size_t)(q0 + qi * 16 + rq) * Dc + c * 32 + kk8);

  floatx4 o_acc[2][4] = {};
  floatx4 acc_l[2] = {};
  float m_run[2][4];
#pragma unroll
  for (int qi = 0; qi < 2; ++qi)
#pragma unroll
    for (int j = 0; j < 4; ++j) m_run[qi][j] = -1e30f;

  short8 ones;
#pragma unroll
  for (int j = 0; j < 8; ++j) ones[j] = (short)0x3F80;  // bf16 1.0

  const float C1 = 0.125f;  // 1/sqrt(64)

  for (int it = 0; it < Sc / 2 / KB; ++it) {
    const int k0 = g * (Sc / 2) + it * KB;
    // stage K [64 keys][64 dk] and V^T [64 dk][64 keys], vectorized
    {
      const unsigned short* ks = Kb + (size_t)(k0 + sr) * Dc + scs;
      *(short8*)&Ks[g][sr * LDK + scs] = *(const short8*)ks;
      *(short8*)&Ks[g][sr * LDK + scs + 8] = *(const short8*)(ks + 8);
      const unsigned short* vs = Vh + (size_t)sr * Sc + k0 + scs;
      *(short8*)&Vs[g][sr * LDV + scs] = *(const short8*)vs;
      *(short8*)&Vs[g][sr * LDV + scs + 8] = *(const short8*)(vs + 8);
    }
    __syncthreads();

#pragma unroll
    for (int qi = 0; qi < 2; ++qi) {
      // QK^T: S[q][key] ; B-frag = K[key][dk] rows of Ks
      floatx4 s4[4] = {};
#pragma unroll
      for (int kt = 0; kt < 4; ++kt) {
        short8 b0 = *(const short8*)&Ks[g][(kt * 16 + rq) * LDK + kk8];
        short8 b1 = *(const short8*)&Ks[g][(kt * 16 + rq) * LDK + 32 + kk8];
        s4[kt] = __builtin_amdgcn_mfma_f32_16x16x32_bf16(qa[qi][0], b0, s4[kt], 0, 0, 0);
        s4[kt] = __builtin_amdgcn_mfma_f32_16x16x32_bf16(qa[qi][1], b1, s4[kt], 0, 0, 0);
      }
      // row max (max first, then single scale mul — monotone)
      float tm[4];
#pragma unroll
      for (int j = 0; j < 4; ++j) {
        float t0 = fmaxf(fmaxf(s4[0][j], s4[1][j]), fmaxf(s4[2][j], s4[3][j]));
        tm[j] = t0 * C1;
      }
#pragma unroll
      for (int mask = 1; mask <= 8; mask <<= 1)
#pragma unroll
        for (int j = 0; j < 4; ++j)
          tm[j] = fmaxf(tm[j], __shfl_xor(tm[j], mask, 64));

      bool grow = false;
#pragma unroll
      for (int j = 0; j < 4; ++j) grow = grow || (tm[j] > m_run[qi][j]);
      if (__any(grow)) {
#pragma unroll
        for (int j = 0; j < 4; ++j) {
          float mn = fmaxf(m_run[qi][j], tm[j]);
          float sc = __expf(m_run[qi][j] - mn);
          m_run[qi][j] = mn;
          acc_l[qi][j] *= sc;
#pragma unroll
          for (int d = 0; d < 4; ++d) o_acc[qi][d][j] *= sc;
        }
      }
      // P = exp(s*C1 - m), spill to wave-private LDS rows
#pragma unroll
      for (int kt = 0; kt < 4; ++kt)
#pragma unroll
        for (int j = 0; j < 4; ++j) {
          float p = __expf(fmaf(s4[kt][j], C1, -m_run[qi][j]));
          Ps[g][((w * 32 + qi * 16 + lg * 4 + j)) * LDPS + kt * 16 + rq] = f2bf(p);
        }
      asm volatile("s_waitcnt lgkmcnt(0)" ::: "memory");
      __builtin_amdgcn_sched_barrier(0);

      // PV: A = P rows (wave-private), B = V^T rows of Vs
      short8 pa0 = *(const short8*)&Ps[g][(w * 32 + qi * 16 + rq) * LDPS + kk8];
      short8 pa1 = *(const short8*)&Ps[g][(w * 32 + qi * 16 + rq) * LDPS + 32 + kk8];
#pragma unroll
      for (int d = 0; d < 4; ++d) {
        short8 v0 = *(const short8*)&Vs[g][(d * 16 + rq) * LDV + kk8];
        short8 v1 = *(const short8*)&Vs[g][(d * 16 + rq) * LDV + 32 + kk8];
        o_acc[qi][d] = __builtin_amdgcn_mfma_f32_16x16x32_bf16(pa0, v0, o_acc[qi][d], 0, 0, 0);
        o_acc[qi][d] = __builtin_amdgcn_mfma_f32_16x16x32_bf16(pa1, v1, o_acc[qi][d], 0, 0, 0);
      }
      acc_l[qi] = __builtin_amdgcn_mfma_f32_16x16x32_bf16(pa0, ones, acc_l[qi], 0, 0, 0);
      acc_l[qi] = __builtin_amdgcn_mfma_f32_16x16x32_bf16(pa1, ones, acc_l[qi], 0, 0, 0);
    }
    __syncthreads();
  }

  // ---- merge the two key-halves ----
  float* MO = (float*)&Ps[0][0];  // 4 waves x 32 rows x 64 cols f32 = 32 KB
  float* ML = (float*)&Ks[0][0];  // 128 rows x {m,l}
  if (g == 1) {
#pragma unroll
    for (int qi = 0; qi < 2; ++qi)
#pragma unroll
      for (int j = 0; j < 4; ++j) {
        int row = w * 32 + qi * 16 + lg * 4 + j;
        ML[row * 2 + 0] = m_run[qi][j];
        ML[row * 2 + 1] = acc_l[qi][j];
#pragma unroll
        for (int d = 0; d < 4; ++d)
          MO[(size_t)row * 64 + d * 16 + rq] = o_acc[qi][d][j];
      }
  }
  __syncthreads();
  if (g == 0) {
#pragma unroll
    for (int qi = 0; qi < 2; ++qi)
#pragma unroll
      for (int j = 0; j < 4; ++j) {
        int row = w * 32 + qi * 16 + lg * 4 + j;
        int r = q0 + qi * 16 + lg * 4 + j;
        float m1 = ML[row * 2 + 0], l1 = ML[row * 2 + 1];
        float m0 = m_run[qi][j], l0 = acc_l[qi][j];
        float mx = fmaxf(m0, m1);
        float a0 = __expf(m0 - mx), a1 = __expf(m1 - mx);
        float inv = 1.0f / (l0 * a0 + l1 * a1);
#pragma unroll
        for (int d = 0; d < 4; ++d) {
          float o = (o_acc[qi][d][j] * a0 + MO[(size_t)row * 64 + d * 16 + rq] * a1) * inv;
          Op[((size_t)b * Sc + r) * Dc + h * DKc + d * 16 + rq] = f2bf(o);
        }
      }
  }
}

// ---------------- launcher --------------------------------------------------
extern "C" void kernel_launch(void* const* d_in, const int* in_sizes, int n_in,
                              void* d_out, int out_size, void* d_ws, size_t ws_size,
                              hipStream_t stream) {
  const float* q_in = (const float*)d_in[0];
  const float* k_in = (const float*)d_in[1];
  const float* v_in = (const float*)d_in[2];
  const float* Wq = (const float*)d_in[3];
  const float* Wk = (const float*)d_in[4];
  const float* Wv = (const float*)d_in[5];
  const float* Wo = (const float*)d_in[6];

  unsigned short* wq_b = (unsigned short*)d_ws;
  unsigned short* wk_b = wq_b + Dc * Dc;
  unsigned short* wv_b = wk_b + Dc * Dc;
  unsigned short* wo_b = wv_b + Dc * Dc;
  unsigned short* qb = wo_b + Dc * Dc;
  unsigned short* kb = qb + (size_t)Mc * Dc;
  unsigned short* vb = kb + (size_t)Mc * Dc;
  unsigned short* ab = vb + (size_t)Mc * Dc;
  unsigned short* vt = ab + (size_t)Mc * Dc;  // V^T per (b): [D][S]

  dim3 cg(Dc * Dc / 4 / 256, 4);
  cast_w<<<cg, 256, 0, stream>>>(Wq, Wk, Wv, Wo, wq_b);

  dim3 gg(Dc / 128, Mc / 128);
  gemm_bt<1, 0><<<gg, 256, 0, stream>>>(q_in, wq_b, qb, Mc, Dc, Dc);
  gemm_bt<1, 0><<<gg, 256, 0, stream>>>(k_in, wk_b, kb, Mc, Dc, Dc);
  gemm_bt<1, 0><<<gg, 256, 0, stream>>>(v_in, wv_b, vb, Mc, Dc, Dc);

  dim3 tg(Sc / 64, Dc / 64, Bc);
  transpose_v<<<tg, 256, 0, stream>>>(vb, vt);

  dim3 ga(Sc / 128, Bc * Hc);  // (32, 16), 512-thread blocks
  attn_fwd<<<ga, 512, 0, stream>>>(qb, kb, vt, ab);

  gemm_bt<0, 1><<<gg, 256, 0, stream>>>(ab, wo_b, (float*)d_out, Mc, Dc, Dc);
}